// Round 16
// baseline (484.491 us; speedup 1.0000x reference)
//
#include <hip/hip_runtime.h>
#include <math.h>

// Problem dims
#define S_LEN 2048
#define D_HEAD 64
#define BH 32
#define ROWS 16
#define STRIPS 8    // strips per persistent block; grid = 512 = 2 blocks/CU

typedef __attribute__((ext_vector_type(8))) short short8;    // 8 bf16 (4 VGPR)
typedef __attribute__((ext_vector_type(4))) short short4v;   // 8B LDS chunk
typedef __attribute__((ext_vector_type(4))) float f32x4;

// LDS row stride in bf16 elems: 4104B rows -> 8B aligned, +2-bank row shift
#define SPAD 2052

__device__ __forceinline__ short f2bf(float f) {
  union { float f; unsigned u; } a; a.f = f;
  unsigned u = a.u;
  unsigned r = (u + 0x7fffu + ((u >> 16) & 1u)) >> 16;   // RNE, no NaNs here
  return (short)r;
}
__device__ __forceinline__ float bf2f(unsigned short h) {
  union { unsigned u; float f; } a; a.u = ((unsigned)h) << 16; return a.f;
}
__device__ __forceinline__ f32x4 ntl4(const float* p) { return __builtin_nontemporal_load((const f32x4*)p); }
__device__ __forceinline__ void  nts4(float* p, f32x4 v) { __builtin_nontemporal_store(v, (f32x4*)p); }

// ---------------------------------------------------------------------------
// Kernel T: K [bh][64][2048] -> kT [bh][2048][64] bf16 ; V [bh][2048][64] ->
// vT [bh][64][2048] bf16. Fully coalesced both sides.
// ---------------------------------------------------------------------------
__global__ __launch_bounds__(256) void transpose_kernel(
    const float* __restrict__ kin, const float* __restrict__ vin,
    unsigned short* __restrict__ kT, unsigned short* __restrict__ vT)
{
  __shared__ float tile[64][65];
  const int bh = blockIdx.y;
  const int bx = blockIdx.x;
  const int t  = threadIdx.x;

  if (blockIdx.z == 0) {
    const float* in = kin + (size_t)bh * D_HEAD * S_LEN;
    #pragma unroll
    for (int p = 0; p < 4; ++p) {
      const int row = p * 16 + (t >> 4);
      f32x4 f = ntl4(in + (size_t)row * S_LEN + bx * 64 + (t & 15) * 4);
      tile[row][(t & 15) * 4 + 0] = f.x; tile[row][(t & 15) * 4 + 1] = f.y;
      tile[row][(t & 15) * 4 + 2] = f.z; tile[row][(t & 15) * 4 + 3] = f.w;
    }
    __syncthreads();
    union { unsigned short h[16]; uint4 q[2]; } u;
    #pragma unroll
    for (int i = 0; i < 16; ++i) u.h[i] = (unsigned short)f2bf(tile[(t & 3) * 16 + i][t >> 2]);
    uint4* dst = (uint4*)(kT + (size_t)bh * S_LEN * D_HEAD
                             + (size_t)(bx * 64 + (t >> 2)) * D_HEAD + (t & 3) * 16);
    dst[0] = u.q[0]; dst[1] = u.q[1];
  } else {
    const float* in = vin + (size_t)bh * S_LEN * D_HEAD;
    #pragma unroll
    for (int p = 0; p < 4; ++p) {
      const int row = p * 16 + (t >> 4);
      f32x4 f = ntl4(in + (size_t)(bx * 64 + row) * D_HEAD + (t & 15) * 4);
      tile[row][(t & 15) * 4 + 0] = f.x; tile[row][(t & 15) * 4 + 1] = f.y;
      tile[row][(t & 15) * 4 + 2] = f.z; tile[row][(t & 15) * 4 + 3] = f.w;
    }
    __syncthreads();
    union { unsigned short h[16]; uint4 q[2]; } u;
    #pragma unroll
    for (int i = 0; i < 16; ++i) u.h[i] = (unsigned short)f2bf(tile[(t & 3) * 16 + i][t >> 2]);
    uint4* dst = (uint4*)(vT + (size_t)bh * D_HEAD * S_LEN
                             + (size_t)(t >> 2) * S_LEN + bx * 64 + (t & 3) * 16);
    dst[0] = u.q[0]; dst[1] = u.q[1];
  }
}

// ---------------------------------------------------------------------------
// Persistent fused kernel: each block owns 8 consecutive 16-row strips of one
// bh. Per strip k:
//  P1  : QK^T MFMA -> bf16(qk) into LDS (its kT-load waits drain pf(k) reads:
//        the strip's prev read happens HERE, overlapping strip k-1's stores)
//  bar
//  P2  : consume pf, scores NT store, e=exp -> LDS, row-sum -> rl (+rlv)
//  bar
//  PV  : 16 k-steps (A = e LDS, B = vT L2)
//  PF  : issue pf(k+1) 32 loads  <- reads of k+1 queued behind k's stores
//  WST : weights = e*rl NT store (own-thread rows; sh.s unchanged since P2)
//  bar ; om alias: merge 4 waves' partial O, scale by rl, NT store; bar
// ---------------------------------------------------------------------------
__global__ __launch_bounds__(256, 2) void fused_kernel(
    const float* __restrict__ q, const unsigned short* __restrict__ kT,
    const float* __restrict__ prev, const float* __restrict__ scale_p,
    const unsigned short* __restrict__ vT,
    float* __restrict__ scores, float* __restrict__ weights, float* __restrict__ outO)
{
  __shared__ union {
    unsigned short s[ROWS][SPAD];   // 65664 B
    float om[4][ROWS][68];          // aliased per-strip after PV/WST barrier
  } sh;
  __shared__ float rlv[ROWS];

  const int bh   = blockIdx.y;
  const int s0   = blockIdx.x * STRIPS;   // first strip index (of 128 per bh)
  const int tid  = threadIdx.x;
  const int w    = tid >> 6;
  const int lane = tid & 63;
  const int lr   = lane & 15;
  const int lg   = lane >> 4;
  const float scale = scale_p[0];

  const int row = tid >> 4;          // P2 row 0..15
  const int cq  = (tid & 15) * 4;    // col chunk base

  const unsigned short* kbase = kT + (size_t)bh * S_LEN * D_HEAD;
  const unsigned short* vbase = vT + (size_t)bh * D_HEAD * S_LEN;
  const size_t bhoff = (size_t)bh * S_LEN * S_LEN;

  // ---- prefetch strip 0's prev (all 32 chunks of this thread's row) ----
  f32x4 pf[32];
  {
    const float* pr0 = prev + bhoff + (size_t)(s0 * ROWS + row) * S_LEN;
    #pragma unroll
    for (int u = 0; u < 32; ++u) pf[u] = ntl4(pr0 + cq + u * 64);
  }

  for (int k = 0; k < STRIPS; ++k) {
    const int m0 = (s0 + k) * ROWS;
    const size_t rowoff = bhoff + (size_t)(m0 + row) * S_LEN;

    // Q A-frags for this strip: row = m0+lr, d = kk*32 + lg*8 + j
    short8 aq[2];
    {
      const float* qrow = q + ((size_t)bh * S_LEN + m0 + lr) * D_HEAD;
      #pragma unroll
      for (int kk = 0; kk < 2; ++kk) {
        f32x4 f0 = *(const f32x4*)(qrow + kk * 32 + lg * 8);
        f32x4 f1 = *(const f32x4*)(qrow + kk * 32 + lg * 8 + 4);
        short8 a;
        a[0]=f2bf(f0.x); a[1]=f2bf(f0.y); a[2]=f2bf(f0.z); a[3]=f2bf(f0.w);
        a[4]=f2bf(f1.x); a[5]=f2bf(f1.y); a[6]=f2bf(f1.z); a[7]=f2bf(f1.w);
        aq[kk] = a;
      }
    }

    // ---------------- P1: QK^T -> LDS (bf16 raw products) ----------------
    #pragma unroll 2
    for (int t8 = 0; t8 < 8; ++t8) {
      const int n0 = w * 512 + t8 * 64;
      f32x4 acc[4];
      #pragma unroll
      for (int nt = 0; nt < 4; ++nt) acc[nt] = (f32x4){0.f, 0.f, 0.f, 0.f};

      #pragma unroll
      for (int kk = 0; kk < 2; ++kk) {
        #pragma unroll
        for (int nt = 0; nt < 4; ++nt) {
          const short8 b = *(const short8*)(
              kbase + (size_t)(n0 + nt * 16 + lr) * D_HEAD + kk * 32 + lg * 8);
          acc[nt] = __builtin_amdgcn_mfma_f32_16x16x32_bf16(aq[kk], b, acc[nt], 0, 0, 0);
        }
      }
      #pragma unroll
      for (int nt = 0; nt < 4; ++nt)
        #pragma unroll
        for (int rg = 0; rg < 4; ++rg)
          sh.s[lg * 4 + rg][n0 + nt * 16 + lr] = (unsigned short)f2bf(acc[nt][rg]);
    }
    __syncthreads();

    // ---------------- P2: consume 32 chunks, scores out, e -> LDS ---------
    float* srow = scores + rowoff;
    float sum = 0.f;
    #pragma unroll
    for (int u = 0; u < 32; ++u) {
      const int c = cq + u * 64;
      const f32x4 p = pf[u];
      short4v h = *(const short4v*)&sh.s[row][c];
      f32x4 s;
      s.x = bf2f((unsigned short)h[0]) * scale + p.x;
      s.y = bf2f((unsigned short)h[1]) * scale + p.y;
      s.z = bf2f((unsigned short)h[2]) * scale + p.z;
      s.w = bf2f((unsigned short)h[3]) * scale + p.w;
      nts4(srow + c, s);
      const float e0 = __expf(s.x), e1 = __expf(s.y), e2 = __expf(s.z), e3 = __expf(s.w);
      sum += (e0 + e1) + (e2 + e3);
      short4v g;
      g[0] = f2bf(e0); g[1] = f2bf(e1); g[2] = f2bf(e2); g[3] = f2bf(e3);
      *(short4v*)&sh.s[row][c] = g;
    }

    // row-sum across the 16-lane group (same wave, aligned)
    #pragma unroll
    for (int msk = 1; msk <= 8; msk <<= 1)
      sum += __shfl_xor(sum, msk, 64);
    const float rl = 1.0f / sum;
    if ((tid & 15) == 0) rlv[row] = rl;   // for the epilogue
    __syncthreads();   // e complete for all rows (and rlv visible)

    // ---------------- PV MFMA (A = e from LDS, B = vT via L2) -------------
    f32x4 accp[4];
    #pragma unroll
    for (int ct = 0; ct < 4; ++ct) accp[ct] = (f32x4){0.f, 0.f, 0.f, 0.f};

    #pragma unroll 2
    for (int i = 0; i < 16; ++i) {
      const int c4 = w * 512 + i * 32 + lg * 8;
      short4v h0 = *(const short4v*)&sh.s[lr][c4];
      short4v h1 = *(const short4v*)&sh.s[lr][c4 + 4];
      short8 a;
      a[0]=h0[0]; a[1]=h0[1]; a[2]=h0[2]; a[3]=h0[3];
      a[4]=h1[0]; a[5]=h1[1]; a[6]=h1[2]; a[7]=h1[3];
      #pragma unroll
      for (int ct = 0; ct < 4; ++ct) {
        const short8 b = *(const short8*)(vbase + (size_t)(ct * 16 + lr) * S_LEN + c4);
        accp[ct] = __builtin_amdgcn_mfma_f32_16x16x32_bf16(a, b, accp[ct], 0, 0, 0);
      }
    }

    // ---------------- PF: issue next strip's prev loads -------------------
    if (k + 1 < STRIPS) {
      const float* prn = prev + bhoff + (size_t)((m0 + ROWS) + row) * S_LEN;
      #pragma unroll
      for (int u = 0; u < 32; ++u) pf[u] = ntl4(prn + cq + u * 64);
    }

    // ---------------- WST: weights = e*rl (own-thread rows) ---------------
    float* wrow = weights + rowoff;
    #pragma unroll
    for (int u = 0; u < 32; ++u) {
      const int c = cq + u * 64;
      short4v hw = *(const short4v*)&sh.s[row][c];
      f32x4 e;
      e.x = bf2f((unsigned short)hw[0]) * rl;
      e.y = bf2f((unsigned short)hw[1]) * rl;
      e.z = bf2f((unsigned short)hw[2]) * rl;
      e.w = bf2f((unsigned short)hw[3]) * rl;
      nts4(wrow + c, e);
    }
    __syncthreads();   // all sh.s reads done; safe to alias sh.om

    // ---------------- epilogue: merge partial O, store --------------------
    #pragma unroll
    for (int ct = 0; ct < 4; ++ct)
      #pragma unroll
      for (int rg = 0; rg < 4; ++rg)
        sh.om[w][lg * 4 + rg][ct * 16 + lr] = accp[ct][rg];
    __syncthreads();

    {
      const int d4 = (tid & 15) * 4;
      const float rls = rlv[row];
      f32x4 v;
      #pragma unroll
      for (int i = 0; i < 4; ++i)
        v[i] = (sh.om[0][row][d4 + i] + sh.om[1][row][d4 + i]
              + sh.om[2][row][d4 + i] + sh.om[3][row][d4 + i]) * rls;
      nts4(outO + ((size_t)bh * S_LEN + m0 + row) * D_HEAD + d4, v);
    }
    __syncthreads();   // om reads done before next strip's P1 overwrites sh.s
  }
}

// ---------------------------------------------------------------------------
extern "C" void kernel_launch(void* const* d_in, const int* in_sizes, int n_in,
                              void* d_out, int out_size, void* d_ws, size_t ws_size,
                              hipStream_t stream)
{
  const float* q     = (const float*)d_in[0];
  const float* kin   = (const float*)d_in[1];
  const float* vin   = (const float*)d_in[2];
  const float* prev  = (const float*)d_in[3];
  const float* scale = (const float*)d_in[4];

  float* O  = (float*)d_out;                                  // [32][2048][64]
  float* W  = O + (size_t)BH * S_LEN * D_HEAD;                // [32][2048][2048]
  float* Sc = W + (size_t)BH * S_LEN * S_LEN;                 // [32][2048][2048]

  unsigned short* kT = (unsigned short*)d_ws;                 // [32][2048][64] bf16
  unsigned short* vT = kT + (size_t)BH * S_LEN * D_HEAD;      // [32][64][2048] bf16

  dim3 tgrid(S_LEN / 64, BH, 2);
  hipLaunchKernelGGL(transpose_kernel, tgrid, dim3(256), 0, stream, kin, vin, kT, vT);

  dim3 grid(S_LEN / ROWS / STRIPS, BH);   // 16 x 32 = 512 blocks (2/CU)
  hipLaunchKernelGGL(fused_kernel, grid, dim3(256), 0, stream,
                     q, kT, prev, scale, vT, Sc, W, O);
}

// Round 17
// 418.847 us; speedup vs baseline: 1.1567x; 1.1567x over previous
//
#include <hip/hip_runtime.h>
#include <math.h>

// Problem dims
#define S_LEN 2048
#define D_HEAD 64
#define BH 32
#define ROWS 16

typedef __attribute__((ext_vector_type(8))) short short8;    // 8 bf16 (4 VGPR)
typedef __attribute__((ext_vector_type(4))) short short4v;   // 8B LDS chunk
typedef __attribute__((ext_vector_type(4))) float f32x4;

// LDS row stride in bf16 elems: 4104B rows -> 8B aligned, +2-bank row shift
#define SPAD 2052

__device__ __forceinline__ short f2bf(float f) {
  union { float f; unsigned u; } a; a.f = f;
  unsigned u = a.u;
  unsigned r = (u + 0x7fffu + ((u >> 16) & 1u)) >> 16;   // RNE, no NaNs here
  return (short)r;
}
__device__ __forceinline__ float bf2f(unsigned short h) {
  union { unsigned u; float f; } a; a.u = ((unsigned)h) << 16; return a.f;
}
__device__ __forceinline__ f32x4 ntl4(const float* p) { return __builtin_nontemporal_load((const f32x4*)p); }
__device__ __forceinline__ void  nts4(float* p, f32x4 v) { __builtin_nontemporal_store(v, (f32x4*)p); }

// ---------------------------------------------------------------------------
// Kernel T: K [bh][64][2048] -> kT [bh][2048][64] bf16 ; V [bh][2048][64] ->
// vT [bh][64][2048] bf16. Fully coalesced both sides.
// ---------------------------------------------------------------------------
__global__ __launch_bounds__(256) void transpose_kernel(
    const float* __restrict__ kin, const float* __restrict__ vin,
    unsigned short* __restrict__ kT, unsigned short* __restrict__ vT)
{
  __shared__ float tile[64][65];
  const int bh = blockIdx.y;
  const int bx = blockIdx.x;
  const int t  = threadIdx.x;

  if (blockIdx.z == 0) {
    const float* in = kin + (size_t)bh * D_HEAD * S_LEN;
    #pragma unroll
    for (int p = 0; p < 4; ++p) {
      const int row = p * 16 + (t >> 4);
      f32x4 f = ntl4(in + (size_t)row * S_LEN + bx * 64 + (t & 15) * 4);
      tile[row][(t & 15) * 4 + 0] = f.x; tile[row][(t & 15) * 4 + 1] = f.y;
      tile[row][(t & 15) * 4 + 2] = f.z; tile[row][(t & 15) * 4 + 3] = f.w;
    }
    __syncthreads();
    union { unsigned short h[16]; uint4 q[2]; } u;
    #pragma unroll
    for (int i = 0; i < 16; ++i) u.h[i] = (unsigned short)f2bf(tile[(t & 3) * 16 + i][t >> 2]);
    uint4* dst = (uint4*)(kT + (size_t)bh * S_LEN * D_HEAD
                             + (size_t)(bx * 64 + (t >> 2)) * D_HEAD + (t & 3) * 16);
    dst[0] = u.q[0]; dst[1] = u.q[1];
  } else {
    const float* in = vin + (size_t)bh * S_LEN * D_HEAD;
    #pragma unroll
    for (int p = 0; p < 4; ++p) {
      const int row = p * 16 + (t >> 4);
      f32x4 f = ntl4(in + (size_t)(bx * 64 + row) * D_HEAD + (t & 15) * 4);
      tile[row][(t & 15) * 4 + 0] = f.x; tile[row][(t & 15) * 4 + 1] = f.y;
      tile[row][(t & 15) * 4 + 2] = f.z; tile[row][(t & 15) * 4 + 3] = f.w;
    }
    __syncthreads();
    union { unsigned short h[16]; uint4 q[2]; } u;
    #pragma unroll
    for (int i = 0; i < 16; ++i) u.h[i] = (unsigned short)f2bf(tile[(t & 3) * 16 + i][t >> 2]);
    uint4* dst = (uint4*)(vT + (size_t)bh * D_HEAD * S_LEN
                             + (size_t)(t >> 2) * S_LEN + bx * 64 + (t & 3) * 16);
    dst[0] = u.q[0]; dst[1] = u.q[1];
  }
}

// ---------------------------------------------------------------------------
// Fused kernel (best configuration, R14):
//  pre : ALL 32 prev chunks issued before P1 (32 loads in flight; they drain
//        during P1's L2/MFMA work)
//  P1  : QK^T MFMA -> bf16(qk) into LDS (C-layout scatter)
//  bar
//  P2  : 32 chunks: consume pf[u], scores NT store, e = exp(s) -> LDS, sum.
//  rl  : 16-lane-group reduce (own wave) -> rl in register
//  WST : weights = e*rl NT store (own row's e, own wave's LDS writes -> no
//        barrier needed; early waves stream stores while others finish P2)
//  bar (e complete for all rows)
//  PV  : 16 k-steps (A = e from LDS, B = vT via L2); stores drain underneath
//  bar ; merge 4 waves' partial O via LDS alias, scale by rl, NT store.
// ---------------------------------------------------------------------------
__global__ __launch_bounds__(256, 2) void fused_kernel(
    const float* __restrict__ q, const unsigned short* __restrict__ kT,
    const float* __restrict__ prev, const float* __restrict__ scale_p,
    const unsigned short* __restrict__ vT,
    float* __restrict__ scores, float* __restrict__ weights, float* __restrict__ outO)
{
  __shared__ union {
    unsigned short s[ROWS][SPAD];   // 65664 B
    float om[4][ROWS][68];          // aliased after PV's LDS reads
  } sh;
  __shared__ float rlv[ROWS];

  const int bh   = blockIdx.y;
  const int m0   = blockIdx.x * ROWS;
  const int tid  = threadIdx.x;
  const int w    = tid >> 6;
  const int lane = tid & 63;
  const int lr   = lane & 15;
  const int lg   = lane >> 4;
  const float scale = scale_p[0];

  // P2 mapping: row owned by an aligned 16-lane group of one wave
  const int row = tid >> 4;          // 0..15
  const int cq  = (tid & 15) * 4;    // 0..60
  const size_t rowoff = (size_t)bh * S_LEN * S_LEN + (size_t)(m0 + row) * S_LEN;
  const float* prevrow = prev + rowoff;

  // ---- maximal prefetch: all 32 chunks of this thread's row ----
  f32x4 pf[32];
  #pragma unroll
  for (int u = 0; u < 32; ++u) pf[u] = ntl4(prevrow + cq + u * 64);

  // Q A-frags: row = m0+lr, d = kk*32 + lg*8 + j
  short8 aq[2];
  {
    const float* qrow = q + ((size_t)bh * S_LEN + m0 + lr) * D_HEAD;
    #pragma unroll
    for (int kk = 0; kk < 2; ++kk) {
      f32x4 f0 = *(const f32x4*)(qrow + kk * 32 + lg * 8);
      f32x4 f1 = *(const f32x4*)(qrow + kk * 32 + lg * 8 + 4);
      short8 a;
      a[0]=f2bf(f0.x); a[1]=f2bf(f0.y); a[2]=f2bf(f0.z); a[3]=f2bf(f0.w);
      a[4]=f2bf(f1.x); a[5]=f2bf(f1.y); a[6]=f2bf(f1.z); a[7]=f2bf(f1.w);
      aq[kk] = a;
    }
  }

  const unsigned short* kbase = kT + (size_t)bh * S_LEN * D_HEAD;

  // ---------------- P1: QK^T -> LDS (bf16 raw products) ----------------
  #pragma unroll 2
  for (int t8 = 0; t8 < 8; ++t8) {
    const int n0 = w * 512 + t8 * 64;
    f32x4 acc[4];
    #pragma unroll
    for (int nt = 0; nt < 4; ++nt) acc[nt] = (f32x4){0.f, 0.f, 0.f, 0.f};

    #pragma unroll
    for (int kk = 0; kk < 2; ++kk) {
      #pragma unroll
      for (int nt = 0; nt < 4; ++nt) {
        const short8 b = *(const short8*)(
            kbase + (size_t)(n0 + nt * 16 + lr) * D_HEAD + kk * 32 + lg * 8);
        acc[nt] = __builtin_amdgcn_mfma_f32_16x16x32_bf16(aq[kk], b, acc[nt], 0, 0, 0);
      }
    }
    #pragma unroll
    for (int nt = 0; nt < 4; ++nt)
      #pragma unroll
      for (int rg = 0; rg < 4; ++rg)
        sh.s[lg * 4 + rg][n0 + nt * 16 + lr] = (unsigned short)f2bf(acc[nt][rg]);
  }
  __syncthreads();

  // ---------------- P2: consume 32 chunks, scores out, e -> LDS -----------
  float* srow = scores + rowoff;
  float sum = 0.f;
  #pragma unroll
  for (int u = 0; u < 32; ++u) {
    const int c = cq + u * 64;
    const f32x4 p = pf[u];
    short4v h = *(const short4v*)&sh.s[row][c];
    f32x4 s;
    s.x = bf2f((unsigned short)h[0]) * scale + p.x;
    s.y = bf2f((unsigned short)h[1]) * scale + p.y;
    s.z = bf2f((unsigned short)h[2]) * scale + p.z;
    s.w = bf2f((unsigned short)h[3]) * scale + p.w;
    nts4(srow + c, s);
    const float e0 = __expf(s.x), e1 = __expf(s.y), e2 = __expf(s.z), e3 = __expf(s.w);
    sum += (e0 + e1) + (e2 + e3);
    short4v g;
    g[0] = f2bf(e0); g[1] = f2bf(e1); g[2] = f2bf(e2); g[3] = f2bf(e3);
    *(short4v*)&sh.s[row][c] = g;
  }

  // row-sum across the 16-lane group (same wave, aligned)
  #pragma unroll
  for (int msk = 1; msk <= 8; msk <<= 1)
    sum += __shfl_xor(sum, msk, 64);
  const float rl = 1.0f / sum;
  if ((tid & 15) == 0) rlv[row] = rl;   // for the epilogue only

  // ---------------- WST: weights = e*rl (own wave's data; pre-barrier) ----
  float* wrow = weights + rowoff;
  #pragma unroll
  for (int u = 0; u < 32; ++u) {
    const int c = cq + u * 64;
    short4v hw = *(const short4v*)&sh.s[row][c];
    f32x4 e;
    e.x = bf2f((unsigned short)hw[0]) * rl;
    e.y = bf2f((unsigned short)hw[1]) * rl;
    e.z = bf2f((unsigned short)hw[2]) * rl;
    e.w = bf2f((unsigned short)hw[3]) * rl;
    nts4(wrow + c, e);
  }
  __syncthreads();   // e in LDS complete for all rows

  // ---------------- PV MFMA (stores drain underneath) ----------------
  const unsigned short* vbase = vT + (size_t)bh * D_HEAD * S_LEN;
  f32x4 accp[4];
  #pragma unroll
  for (int ct = 0; ct < 4; ++ct) accp[ct] = (f32x4){0.f, 0.f, 0.f, 0.f};

  #pragma unroll 2
  for (int i = 0; i < 16; ++i) {
    const int c4 = w * 512 + i * 32 + lg * 8;
    short4v h0 = *(const short4v*)&sh.s[lr][c4];
    short4v h1 = *(const short4v*)&sh.s[lr][c4 + 4];
    short8 a;
    a[0]=h0[0]; a[1]=h0[1]; a[2]=h0[2]; a[3]=h0[3];
    a[4]=h1[0]; a[5]=h1[1]; a[6]=h1[2]; a[7]=h1[3];
    #pragma unroll
    for (int ct = 0; ct < 4; ++ct) {
      const short8 b = *(const short8*)(vbase + (size_t)(ct * 16 + lr) * S_LEN + c4);
      accp[ct] = __builtin_amdgcn_mfma_f32_16x16x32_bf16(a, b, accp[ct], 0, 0, 0);
    }
  }
  __syncthreads();   // all sh.s reads done; safe to alias sh.om

  #pragma unroll
  for (int ct = 0; ct < 4; ++ct)
    #pragma unroll
    for (int rg = 0; rg < 4; ++rg)
      sh.om[w][lg * 4 + rg][ct * 16 + lr] = accp[ct][rg];
  __syncthreads();

  {
    const int d4 = (tid & 15) * 4;
    const float rls = rlv[row];
    f32x4 v;
    #pragma unroll
    for (int i = 0; i < 4; ++i)
      v[i] = (sh.om[0][row][d4 + i] + sh.om[1][row][d4 + i]
            + sh.om[2][row][d4 + i] + sh.om[3][row][d4 + i]) * rls;
    nts4(outO + ((size_t)bh * S_LEN + m0 + row) * D_HEAD + d4, v);
  }
}

// ---------------------------------------------------------------------------
extern "C" void kernel_launch(void* const* d_in, const int* in_sizes, int n_in,
                              void* d_out, int out_size, void* d_ws, size_t ws_size,
                              hipStream_t stream)
{
  const float* q     = (const float*)d_in[0];
  const float* kin   = (const float*)d_in[1];
  const float* vin   = (const float*)d_in[2];
  const float* prev  = (const float*)d_in[3];
  const float* scale = (const float*)d_in[4];

  float* O  = (float*)d_out;                                  // [32][2048][64]
  float* W  = O + (size_t)BH * S_LEN * D_HEAD;                // [32][2048][2048]
  float* Sc = W + (size_t)BH * S_LEN * S_LEN;                 // [32][2048][2048]

  unsigned short* kT = (unsigned short*)d_ws;                 // [32][2048][64] bf16
  unsigned short* vT = kT + (size_t)BH * S_LEN * D_HEAD;      // [32][64][2048] bf16

  dim3 tgrid(S_LEN / 64, BH, 2);
  hipLaunchKernelGGL(transpose_kernel, tgrid, dim3(256), 0, stream, kin, vin, kT, vT);

  dim3 grid(S_LEN / ROWS, BH);
  hipLaunchKernelGGL(fused_kernel, grid, dim3(256), 0, stream,
                     q, kT, prev, scale, vT, Sc, W, O);
}